// Round 4
// baseline (3572.125 us; speedup 1.0000x reference)
//
#include <hip/hip_runtime.h>
#include <hip/hip_bf16.h>
#include <cmath>

typedef __hip_bfloat16 bf16;

#define D_ 768
#define NTOK 16384      // B * N = 16 * 1024
#define INNER_ 192
#define HID_ 3072

__device__ __forceinline__ float b2f(bf16 h) { return __bfloat162float(h); }
__device__ __forceinline__ bf16 f2b(float f) { return __float2bfloat16(f); }
__device__ __forceinline__ float lo2f(unsigned u) { return __uint_as_float(u << 16); }
__device__ __forceinline__ float hi2f(unsigned u) { return __uint_as_float(u & 0xffff0000u); }

// Flag-aware loads/stores: harness tensors are f32 (flag=1) or bf16 (flag=0).
__device__ __forceinline__ float ld1(const void* p, size_t i, int f32) {
  return f32 ? ((const float*)p)[i] : b2f(((const bf16*)p)[i]);
}
__device__ __forceinline__ void ld4(const void* p, size_t i, int f32, float o[4]) {
  if (f32) {
    const float4 t = *(const float4*)((const float*)p + i);  // i%4==0 at call sites
    o[0] = t.x; o[1] = t.y; o[2] = t.z; o[3] = t.w;
  } else {
    const uint2 u = *(const uint2*)((const bf16*)p + i);
    o[0] = lo2f(u.x); o[1] = hi2f(u.x); o[2] = lo2f(u.y); o[3] = hi2f(u.y);
  }
}
__device__ __forceinline__ void st1(void* p, size_t i, float v, int f32) {
  if (f32) ((float*)p)[i] = v; else ((bf16*)p)[i] = f2b(v);
}

// ---------------------------------------------------------------------------
// Dtype detector: bf16 data -> low 16 bits of each 32-bit word form a sane
// bf16 (exp field in [96,144]) ~100% of the time; f32 data -> low bits are
// mantissa noise (~19% hit rate). Vote over 512 words. flag: 1=f32, 0=bf16.
// ---------------------------------------------------------------------------
__global__ __launch_bounds__(64) void detect_kernel(const unsigned* __restrict__ x,
                                                    int* __restrict__ flag) {
  int cnt = 0;
  for (int i = threadIdx.x; i < 512; i += 64) {
    const unsigned e0 = (x[i] >> 7) & 0xFFu;
    if (e0 >= 96u && e0 <= 144u) cnt++;
  }
#pragma unroll
  for (int o = 32; o > 0; o >>= 1) cnt += __shfl_down(cnt, o);
  if (threadIdx.x == 0) flag[0] = (cnt < 256) ? 1 : 0;
}

// ---------------------------------------------------------------------------
// Per-token LayerNorm stats (mu, 1/sigma). One wave per token.
// AF=1: input is a harness tensor (flag dtype). AF=0: internal bf16.
// ---------------------------------------------------------------------------
template <int AF>
__global__ __launch_bounds__(256) void ln_stats_kernel(const void* __restrict__ x,
                                                       float* __restrict__ mu_o,
                                                       float* __restrict__ rs_o,
                                                       const int* __restrict__ flagp) {
  const int f32 = AF ? flagp[0] : 0;
  const int t = blockIdx.x * 4 + (threadIdx.x >> 6);
  const int lane = threadIdx.x & 63;
  float s = 0.f, s2 = 0.f;
#pragma unroll
  for (int i = 0; i < 12; i++) {            // 12 * 64 = 768
    const float v = ld1(x, (size_t)t * D_ + i * 64 + lane, f32);
    s += v;
    s2 += v * v;
  }
#pragma unroll
  for (int o = 32; o > 0; o >>= 1) {
    s += __shfl_down(s, o);
    s2 += __shfl_down(s2, o);
  }
  if (lane == 0) {
    const float mu = s * (1.f / D_);
    const float var = s2 * (1.f / D_) - mu * mu;
    mu_o[t] = mu;
    rs_o[t] = rsqrtf(var + 1e-5f);
  }
}

// ---------------------------------------------------------------------------
// GEMM: C[row0+M x N] = op(A)[M x K] * B[N x K]^T + bias.  f32 accumulate.
// B, bias, lnw, lnb always harness tensors (flag dtype).
// AF/RF/CF: 1 = operand uses flag dtype, 0 = internal bf16.
// LNA=1: A elements get (a - mu[row]) * rs[row] * lnw[k] + lnb[k].
// EPI 0: C=acc+bias | 1: gelu(acc+bias) | 2: acc+bias+res
// res/C are indexed at (row0+row)*N+col; A at row*K.
// ---------------------------------------------------------------------------
__device__ __forceinline__ float gelu_exact(float v) {
  return 0.5f * v * (1.f + erff(v * 0.7071067811865476f));
}

template <int EPI, int LNA, int AF, int RF, int CF>
__global__ __launch_bounds__(256) void gemm_bt(const void* __restrict__ A,
                                               const void* __restrict__ B,
                                               const void* __restrict__ bias,
                                               const void* __restrict__ res,
                                               void* __restrict__ C,
                                               int N, int K, int row0,
                                               const float* __restrict__ mu,
                                               const float* __restrict__ rs,
                                               const void* __restrict__ lnw,
                                               const void* __restrict__ lnb,
                                               const int* __restrict__ flagp) {
  const int fl = flagp[0];
  const int af = AF ? fl : 0;
  const int rf = RF ? fl : 0;
  const int cf = CF ? fl : 0;
  __shared__ float As[16][65];  // +1 pad: 2-way bank aliasing only (free)
  __shared__ float Bs[16][65];
  const int tid = threadIdx.x;
  const int bm = blockIdx.x * 64;
  const int bn = blockIdx.y * 64;
  const int lrow = tid >> 2;         // 0..63
  const int lk = (tid & 3) << 2;     // 0,4,8,12
  const int ty = (tid >> 4) << 2;    // 0..60 step 4
  const int tx = (tid & 15) << 2;    // 0..60 step 4
  const size_t abase = (size_t)(bm + lrow) * K + lk;
  const size_t bbase = (size_t)(bn + lrow) * K + lk;
  float rmu = 0.f, rrs = 0.f;
  if (LNA) { rmu = mu[bm + lrow]; rrs = rs[bm + lrow]; }
  float acc[4][4] = {};
  for (int k0 = 0; k0 < K; k0 += 16) {
    float a[4], b[4];
    ld4(A, abase + k0, af, a);
    ld4(B, bbase + k0, fl, b);
    if (LNA) {
      float w[4], u[4];
      ld4(lnw, (size_t)(k0 + lk), fl, w);
      ld4(lnb, (size_t)(k0 + lk), fl, u);
#pragma unroll
      for (int i = 0; i < 4; i++) a[i] = (a[i] - rmu) * rrs * w[i] + u[i];
    }
    __syncthreads();  // previous iteration's LDS reads complete
#pragma unroll
    for (int i = 0; i < 4; i++) {
      As[lk + i][lrow] = a[i];
      Bs[lk + i][lrow] = b[i];
    }
    __syncthreads();
#pragma unroll
    for (int kk = 0; kk < 16; ++kk) {
      float av[4], bv[4];
#pragma unroll
      for (int i = 0; i < 4; i++) av[i] = As[kk][ty + i];
#pragma unroll
      for (int j = 0; j < 4; j++) bv[j] = Bs[kk][tx + j];
#pragma unroll
      for (int i = 0; i < 4; i++)
#pragma unroll
        for (int j = 0; j < 4; j++) acc[i][j] += av[i] * bv[j];
    }
  }
#pragma unroll
  for (int i = 0; i < 4; i++) {
    const size_t orow = (size_t)row0 + bm + ty + i;
#pragma unroll
    for (int j = 0; j < 4; j++) {
      const int col = bn + tx + j;
      float v = acc[i][j] + ld1(bias, col, fl);
      if (EPI == 1) v = gelu_exact(v);
      if (EPI == 2) v += ld1(res, orow * N + col, rf);
      st1(C, orow * N + col, v, cf);
    }
  }
}

// ---------------------------------------------------------------------------
// Cluster kernel: one block (256 thr) per (batch, head); 128 blocks.
// F, V, CL: internal bf16 (B, N=1024, 192), head channels at e*24.
// ---------------------------------------------------------------------------
__global__ __launch_bounds__(256) void cluster_kernel(const bf16* __restrict__ F,
                                                      const bf16* __restrict__ V,
                                                      const void* __restrict__ alpha_p,
                                                      const void* __restrict__ beta_p,
                                                      bf16* __restrict__ CL,
                                                      const int* __restrict__ flagp) {
  const int fl = flagp[0];
  const int be = blockIdx.x;       // 0..127
  const int b = be >> 3, e = be & 7;
  const int tid = threadIdx.x;
  const float alpha = ld1(alpha_p, 0, fl), beta = ld1(beta_p, 0, fl);

  __shared__ float cn[16][24];     // f centers, normalized in place
  __shared__ float vcen[16][24];   // v centers
  __shared__ float outc[16][24];   // reduced center features
  __shared__ float cnorm[16];
  __shared__ int cnt[16];
  __shared__ int sm_m[1024];       // per-token argmax center
  __shared__ float sm_s[1024];     // per-token sim at argmax

  const bf16* Fb = F + ((size_t)b * 1024) * 192 + e * 24;
  const bf16* Vb = V + ((size_t)b * 1024) * 192 + e * 24;

  // Phase 1: 8x8 avg-pool centers for f and v. 768 tasks.
  for (int t = tid; t < 768; t += 256) {
    const int kind = t / 384;
    const int rem = t - kind * 384;
    const int m = rem / 24, ch = rem - m * 24;
    const int pw = m >> 2, ph = m & 3;        // m = pw*4 + ph
    const bf16* S = kind ? Vb : Fb;
    float sum = 0.f;
    for (int dw = 0; dw < 8; dw++) {
      const int base = (pw * 8 + dw) * 32 + ph * 8;  // n = w*32 + h
      for (int dh = 0; dh < 8; dh++) sum += b2f(S[(size_t)(base + dh) * 192 + ch]);
    }
    const float mean = sum * (1.f / 64.f);
    if (kind) vcen[m][ch] = mean; else cn[m][ch] = mean;
  }
  if (tid < 16) cnt[tid] = 0;
  __syncthreads();
  if (tid < 16) {
    float s = 0.f;
    for (int ch = 0; ch < 24; ch++) { const float v = cn[tid][ch]; s += v * v; }
    cnorm[tid] = fmaxf(sqrtf(s), 1e-12f);
  }
  __syncthreads();
  for (int t = tid; t < 384; t += 256) {
    const int m = t / 24, ch = t - m * 24;
    cn[m][ch] /= cnorm[m];
  }
  __syncthreads();

  // Phase 2: per-token normalize, sim to 16 centers, argmax (first-max rule)
  for (int n = tid; n < 1024; n += 256) {
    float xf[24];
    float s = 0.f;
#pragma unroll
    for (int ch = 0; ch < 24; ch++) {
      xf[ch] = b2f(Fb[(size_t)n * 192 + ch]);
      s += xf[ch] * xf[ch];
    }
    const float rn = 1.f / fmaxf(sqrtf(s), 1e-12f);
    float best = -3.4e38f;
    int bm_ = 0;
    for (int m = 0; m < 16; m++) {
      float dot = 0.f;
#pragma unroll
      for (int ch = 0; ch < 24; ch++) dot += cn[m][ch] * xf[ch];
      dot *= rn;
      const float d = sqrtf(fmaxf(2.f - 2.f * dot, 1e-12f));
      const float z = beta + alpha * expf(-d);
      const float sim = (z >= 0.f) ? z : 0.2f * z;
      if (sim > best) { best = sim; bm_ = m; }
    }
    sm_m[n] = bm_;
    sm_s[n] = best;
    atomicAdd(&cnt[bm_], 1);
  }
  __syncthreads();

  // Phase 3: masked weighted reduce of V to centers; add vcen; / (count+1)
  for (int t = tid; t < 384; t += 256) {
    const int m = t / 24, ch = t - m * 24;
    float acc = 0.f;
    for (int n = 0; n < 1024; n++) {
      if (sm_m[n] == m) acc += sm_s[n] * b2f(Vb[(size_t)n * 192 + ch]);
    }
    outc[m][ch] = (acc + vcen[m][ch]) / ((float)cnt[m] + 1.f);
  }
  __syncthreads();

  // Phase 4: broadcast back to tokens
  bf16* CLb = CL + ((size_t)b * 1024) * 192 + e * 24;
  for (int n = tid; n < 1024; n += 256) {
    const int m = sm_m[n];
    const float s = sm_s[n];
#pragma unroll
    for (int ch = 0; ch < 24; ch++) CLb[(size_t)n * 192 + ch] = f2b(s * outc[m][ch]);
  }
}

// ---------------------------------------------------------------------------
// Workspace (floor ~44.7 MB; G chunk adapts to ws_size):
//   flag @0 | st1_mu @1024 | st1_rs @66560 | st2_mu @132096 | st2_rs @197632
//   F bf16 @263168 | V bf16 @6554624 | CL bf16 @12846080
//   Hb bf16 16384x768 @19137536 | G bf16 crows*3072 @44303360
// ---------------------------------------------------------------------------
extern "C" void kernel_launch(void* const* d_in, const int* in_sizes, int n_in,
                              void* d_out, int out_size, void* d_ws, size_t ws_size,
                              hipStream_t stream) {
  const void* x      = d_in[0];
  const void* ln1_w  = d_in[1];
  const void* ln1_b  = d_in[2];
  const void* f_w    = d_in[3];
  const void* f_b    = d_in[4];
  const void* v_w    = d_in[5];
  const void* v_b    = d_in[6];
  const void* proj_w = d_in[7];
  const void* proj_b = d_in[8];
  const void* alpha  = d_in[9];
  const void* beta   = d_in[10];
  const void* ln2_w  = d_in[11];
  const void* ln2_b  = d_in[12];
  const void* fc1_w  = d_in[13];
  const void* fc1_b  = d_in[14];
  const void* fc2_w  = d_in[15];
  const void* fc2_b  = d_in[16];

  char* ws = (char*)d_ws;
  int*   flag   = (int*)(ws + 0);
  float* st1_mu = (float*)(ws + 1024);
  float* st1_rs = (float*)(ws + 66560);
  float* st2_mu = (float*)(ws + 132096);
  float* st2_rs = (float*)(ws + 197632);
  bf16*  Fb = (bf16*)(ws + 263168);
  bf16*  Vb = (bf16*)(ws + 6554624);
  bf16*  CL = (bf16*)(ws + 12846080);
  bf16*  Hb = (bf16*)(ws + 19137536);
  bf16*  G  = (bf16*)(ws + 44303360);

  long budget = (long)ws_size - 44303360L;
  long crows = 64;
  if (budget >= 64L * HID_ * 2) {
    crows = (budget / (HID_ * 2)) / 64 * 64;
    if (crows > NTOK) crows = NTOK;
  }

  detect_kernel<<<1, 64, 0, stream>>>((const unsigned*)x, flag);
  ln_stats_kernel<1><<<NTOK / 4, 256, 0, stream>>>(x, st1_mu, st1_rs, flag);
  gemm_bt<0, 1, 1, 0, 0><<<dim3(NTOK / 64, INNER_ / 64), 256, 0, stream>>>(
      x, f_w, f_b, nullptr, Fb, INNER_, D_, 0, st1_mu, st1_rs, ln1_w, ln1_b, flag);
  gemm_bt<0, 1, 1, 0, 0><<<dim3(NTOK / 64, INNER_ / 64), 256, 0, stream>>>(
      x, v_w, v_b, nullptr, Vb, INNER_, D_, 0, st1_mu, st1_rs, ln1_w, ln1_b, flag);
  cluster_kernel<<<128, 256, 0, stream>>>(Fb, Vb, alpha, beta, CL, flag);
  gemm_bt<2, 0, 0, 1, 0><<<dim3(NTOK / 64, D_ / 64), 256, 0, stream>>>(
      CL, proj_w, proj_b, x, Hb, D_, INNER_, 0, nullptr, nullptr, nullptr, nullptr, flag);
  ln_stats_kernel<0><<<NTOK / 4, 256, 0, stream>>>(Hb, st2_mu, st2_rs, flag);
  for (long t0 = 0; t0 < NTOK; t0 += crows) {
    const long ct = (t0 + crows <= NTOK) ? crows : (NTOK - t0);
    gemm_bt<1, 1, 0, 0, 0><<<dim3(ct / 64, HID_ / 64), 256, 0, stream>>>(
        Hb + t0 * D_, fc1_w, fc1_b, nullptr, G, HID_, D_, 0,
        st2_mu + t0, st2_rs + t0, ln2_w, ln2_b, flag);
    // fc2: A = G rows [0,ct); res = Hb rows [t0,..); C = d_out rows [t0,..)
    gemm_bt<2, 0, 0, 0, 1><<<dim3(ct / 64, D_ / 64), 256, 0, stream>>>(
        G, fc2_w, fc2_b, Hb, d_out, D_, HID_, (int)t0,
        nullptr, nullptr, nullptr, nullptr, flag);
  }
}

// Round 5
// 711.954 us; speedup vs baseline: 5.0174x; 5.0174x over previous
//
#include <hip/hip_runtime.h>
#include <hip/hip_bf16.h>
#include <cmath>

typedef unsigned short u16;
typedef short short8 __attribute__((ext_vector_type(8)));   // 8 bf16 (4 VGPRs)
typedef float f32x4 __attribute__((ext_vector_type(4)));    // 4 fp32 acc

#define D_ 768
#define NTOK 16384      // B * N = 16 * 1024
#define INNER_ 192
#define HID_ 3072

__device__ __forceinline__ float u2f(u16 u) { return __uint_as_float((unsigned)u << 16); }
__device__ __forceinline__ u16 f2u(float f) {
  __hip_bfloat16 h = __float2bfloat16(f);
  u16 u; __builtin_memcpy(&u, &h, 2); return u;
}
// Flag-aware scalar load/store: harness tensors are f32 (flag=1) or bf16 (0).
__device__ __forceinline__ float ld1(const void* p, size_t i, int f32) {
  return f32 ? ((const float*)p)[i] : u2f(((const u16*)p)[i]);
}
__device__ __forceinline__ void st1(void* p, size_t i, float v, int f32) {
  if (f32) ((float*)p)[i] = v; else ((u16*)p)[i] = f2u(v);
}
__device__ __forceinline__ float gelu_exact(float v) {
  return 0.5f * v * (1.f + erff(v * 0.7071067811865476f));
}

// ---------------------------------------------------------------------------
// Dtype detector (worked in round 4): flag 1 = f32 inputs, 0 = bf16 inputs.
// ---------------------------------------------------------------------------
__global__ __launch_bounds__(64) void detect_kernel(const unsigned* __restrict__ x,
                                                    int* __restrict__ flag) {
  int cnt = 0;
  for (int i = threadIdx.x; i < 512; i += 64) {
    const unsigned e0 = (x[i] >> 7) & 0xFFu;
    if (e0 >= 96u && e0 <= 144u) cnt++;
  }
#pragma unroll
  for (int o = 32; o > 0; o >>= 1) cnt += __shfl_down(cnt, o);
  if (threadIdx.x == 0) flag[0] = (cnt < 256) ? 1 : 0;
}

// ---------------------------------------------------------------------------
// Weight conversion to internal bf16 (10 jobs; grid.y = job id).
// ---------------------------------------------------------------------------
struct CvtJob { const void* src; u16* dst; int n4; };  // n4 = elems/4
struct CvtArgs { CvtJob j[10]; };

__global__ __launch_bounds__(256) void cvt_kernel(CvtArgs a, const int* __restrict__ flagp) {
  const int f32 = flagp[0];
  const CvtJob jb = a.j[blockIdx.y];
  const int i = blockIdx.x * 256 + threadIdx.x;
  if (i >= jb.n4) return;
  if (f32) {
    const float4 v = ((const float4*)jb.src)[i];
    const unsigned lo = (unsigned)f2u(v.x) | ((unsigned)f2u(v.y) << 16);
    const unsigned hi = (unsigned)f2u(v.z) | ((unsigned)f2u(v.w) << 16);
    ((uint2*)jb.dst)[i] = make_uint2(lo, hi);
  } else {
    ((uint2*)jb.dst)[i] = ((const uint2*)jb.src)[i];
  }
}

// ---------------------------------------------------------------------------
// Fused LayerNorm: stats + normalize, one block (256 thr) per token.
// Input flag dtype, ln params flag dtype, output internal bf16.
// ---------------------------------------------------------------------------
__global__ __launch_bounds__(256) void ln_kernel(const void* __restrict__ x,
                                                 const void* __restrict__ w,
                                                 const void* __restrict__ b,
                                                 u16* __restrict__ y,
                                                 const int* __restrict__ flagp) {
  const int fl = flagp[0];
  const size_t t = blockIdx.x;
  float v[3];
  float s = 0.f, s2 = 0.f;
#pragma unroll
  for (int i = 0; i < 3; i++) {
    v[i] = ld1(x, t * D_ + threadIdx.x + 256 * i, fl);
    s += v[i];
    s2 += v[i] * v[i];
  }
#pragma unroll
  for (int o = 32; o > 0; o >>= 1) {
    s += __shfl_down(s, o);
    s2 += __shfl_down(s2, o);
  }
  __shared__ float ps[4], ps2[4];
  __shared__ float smu, srstd;
  const int wid = threadIdx.x >> 6, lane = threadIdx.x & 63;
  if (lane == 0) { ps[wid] = s; ps2[wid] = s2; }
  __syncthreads();
  if (threadIdx.x == 0) {
    const float a = ps[0] + ps[1] + ps[2] + ps[3];
    const float a2 = ps2[0] + ps2[1] + ps2[2] + ps2[3];
    const float mu = a * (1.f / D_);
    smu = mu;
    srstd = rsqrtf(a2 * (1.f / D_) - mu * mu + 1e-5f);
  }
  __syncthreads();
  const float mu = smu, rstd = srstd;
#pragma unroll
  for (int i = 0; i < 3; i++) {
    const int c = threadIdx.x + 256 * i;
    y[t * D_ + c] = f2u((v[i] - mu) * rstd * ld1(w, c, fl) + ld1(b, c, fl));
  }
}

// ---------------------------------------------------------------------------
// MFMA GEMM (m97 structure): C[M x N] = A[M x K] * B[N x K]^T + bias.
// A, B internal bf16 (u16), row strides lda/ldb (elements), K % 32 == 0.
// 128x128 tile, 4 waves, each wave 4x4 grid of 16x16x32 MFMA tiles.
// Staging: global_load_lds width 16, LDS [128][32] bf16 row-major (no pad).
// EPI 0: C bf16 = acc+bias | 1: C bf16 = gelu(acc+bias)
// EPI 2: C flagdt = acc+bias + res_flagdt   (res may alias C; same-lane RMW)
// res/C rows offset by row0.
// ---------------------------------------------------------------------------
template <int EPI>
__global__ __launch_bounds__(256) void mfma_gemm(const u16* __restrict__ A, int lda,
                                                 const u16* __restrict__ B, int ldb,
                                                 const u16* __restrict__ bias,
                                                 const void* __restrict__ res,
                                                 void* __restrict__ C, int ldc,
                                                 int K, int row0,
                                                 const int* __restrict__ flagp) {
  const int fl = flagp[0];
  __shared__ __align__(16) u16 Asb[128 * 32];
  __shared__ __align__(16) u16 Bsb[128 * 32];
  const int tid = threadIdx.x;
  const int lane = tid & 63;
  const int wv = tid >> 6;
  const int bm = blockIdx.x * 128;
  const int bn = blockIdx.y * 128;
  const int wm = (wv & 1) * 64;
  const int wn = (wv >> 1) * 64;
  // Staging chunks: chunk c (8 bf16) -> row c>>2, k-off (c&3)*8; LDS byte c*16.
  // Per wave, lane l handles chunk w*64+l => LDS contiguous in lane order (req).
  const int c0 = tid, c1 = tid + 256;
  const u16* Ag0 = A + (size_t)(bm + (c0 >> 2)) * lda + (c0 & 3) * 8;
  const u16* Ag1 = A + (size_t)(bm + (c1 >> 2)) * lda + (c1 & 3) * 8;
  const u16* Bg0 = B + (size_t)(bn + (c0 >> 2)) * ldb + (c0 & 3) * 8;
  const u16* Bg1 = B + (size_t)(bn + (c1 >> 2)) * ldb + (c1 & 3) * 8;
  u16* la0 = &Asb[c0 * 8];
  u16* la1 = &Asb[c1 * 8];
  u16* lb0 = &Bsb[c0 * 8];
  u16* lb1 = &Bsb[c1 * 8];

  f32x4 acc[4][4];
#pragma unroll
  for (int i = 0; i < 4; i++)
#pragma unroll
    for (int j = 0; j < 4; j++) acc[i][j] = (f32x4){0.f, 0.f, 0.f, 0.f};

  const int ml = lane & 15;
  const int kq = (lane >> 4) * 8;

  for (int k0 = 0; k0 < K; k0 += 32) {
    __syncthreads();  // all waves done reading previous tile
    __builtin_amdgcn_global_load_lds(
        (const __attribute__((address_space(1))) void*)(Ag0 + k0),
        (__attribute__((address_space(3))) void*)la0, 16, 0, 0);
    __builtin_amdgcn_global_load_lds(
        (const __attribute__((address_space(1))) void*)(Ag1 + k0),
        (__attribute__((address_space(3))) void*)la1, 16, 0, 0);
    __builtin_amdgcn_global_load_lds(
        (const __attribute__((address_space(1))) void*)(Bg0 + k0),
        (__attribute__((address_space(3))) void*)lb0, 16, 0, 0);
    __builtin_amdgcn_global_load_lds(
        (const __attribute__((address_space(1))) void*)(Bg1 + k0),
        (__attribute__((address_space(3))) void*)lb1, 16, 0, 0);
    __syncthreads();  // vmcnt(0) drain => staging complete
    short8 af[4], bf[4];
#pragma unroll
    for (int i = 0; i < 4; i++) {
      af[i] = *(const short8*)&Asb[(wm + i * 16 + ml) * 32 + kq];
      bf[i] = *(const short8*)&Bsb[(wn + i * 16 + ml) * 32 + kq];
    }
#pragma unroll
    for (int i = 0; i < 4; i++)
#pragma unroll
      for (int j = 0; j < 4; j++)
        acc[i][j] = __builtin_amdgcn_mfma_f32_16x16x32_bf16(af[i], bf[j], acc[i][j], 0, 0, 0);
  }

  // Epilogue. C/D layout: col = lane&15, row = (lane>>4)*4 + reg.
  const int qr = (lane >> 4) * 4;
#pragma unroll
  for (int i = 0; i < 4; i++) {
#pragma unroll
    for (int j = 0; j < 4; j++) {
      const int colg = bn + wn + j * 16 + ml;
      const float bb = u2f(bias[colg]);
#pragma unroll
      for (int r = 0; r < 4; r++) {
        const size_t row = (size_t)row0 + bm + wm + i * 16 + qr + r;
        float v = acc[i][j][r] + bb;
        if (EPI == 1) v = gelu_exact(v);
        if (EPI == 2) {
          v += ld1(res, row * ldc + colg, fl);
          st1(C, row * ldc + colg, v, fl);
        } else {
          ((u16*)C)[row * ldc + colg] = f2u(v);
        }
      }
    }
  }
}

// ---------------------------------------------------------------------------
// Cluster kernel: one block (256 thr) per (batch, head); 128 blocks.
// FV: internal bf16 (B*N=16384 tokens x 384): cols [0,192) = f, [192,384) = v.
// Writes CL in place into the f-columns (block-exclusive slice; phases sync'd).
// ---------------------------------------------------------------------------
__global__ __launch_bounds__(256) void cluster_kernel(u16* __restrict__ FV,
                                                      const void* __restrict__ alpha_p,
                                                      const void* __restrict__ beta_p,
                                                      const int* __restrict__ flagp) {
  const int fl = flagp[0];
  const int be = blockIdx.x;       // 0..127
  const int b = be >> 3, e = be & 7;
  const int tid = threadIdx.x;
  const float alpha = ld1(alpha_p, 0, fl), beta = ld1(beta_p, 0, fl);

  __shared__ float cn[16][24];     // f centers, normalized in place
  __shared__ float vcen[16][24];   // v centers
  __shared__ float outc[16][24];   // reduced center features
  __shared__ float cnorm[16];
  __shared__ int cnt[16];
  __shared__ int sm_m[1024];       // per-token argmax center
  __shared__ float sm_s[1024];     // per-token sim at argmax

  u16* Fb = FV + ((size_t)b * 1024) * 384 + e * 24;
  const u16* Vb = Fb + 192;

  // Phase 1: 8x8 avg-pool centers for f and v. 768 tasks.
  for (int t = tid; t < 768; t += 256) {
    const int kind = t / 384;
    const int rem = t - kind * 384;
    const int m = rem / 24, ch = rem - m * 24;
    const int pw = m >> 2, ph = m & 3;        // m = pw*4 + ph
    const u16* S = kind ? Vb : Fb;
    float sum = 0.f;
    for (int dw = 0; dw < 8; dw++) {
      const int base = (pw * 8 + dw) * 32 + ph * 8;  // n = w*32 + h
      for (int dh = 0; dh < 8; dh++) sum += u2f(S[(size_t)(base + dh) * 384 + ch]);
    }
    const float mean = sum * (1.f / 64.f);
    if (kind) vcen[m][ch] = mean; else cn[m][ch] = mean;
  }
  if (tid < 16) cnt[tid] = 0;
  __syncthreads();
  if (tid < 16) {
    float s = 0.f;
    for (int ch = 0; ch < 24; ch++) { const float v = cn[tid][ch]; s += v * v; }
    cnorm[tid] = fmaxf(sqrtf(s), 1e-12f);
  }
  __syncthreads();
  for (int t = tid; t < 384; t += 256) {
    const int m = t / 24, ch = t - m * 24;
    cn[m][ch] /= cnorm[m];
  }
  __syncthreads();

  // Phase 2: per-token normalize, sim to 16 centers, argmax (first-max rule)
  for (int n = tid; n < 1024; n += 256) {
    float xf[24];
    float s = 0.f;
#pragma unroll
    for (int ch = 0; ch < 24; ch++) {
      xf[ch] = u2f(Fb[(size_t)n * 384 + ch]);
      s += xf[ch] * xf[ch];
    }
    const float rn = 1.f / fmaxf(sqrtf(s), 1e-12f);
    float best = -3.4e38f;
    int bm_ = 0;
    for (int m = 0; m < 16; m++) {
      float dot = 0.f;
#pragma unroll
      for (int ch = 0; ch < 24; ch++) dot += cn[m][ch] * xf[ch];
      dot *= rn;
      const float d = sqrtf(fmaxf(2.f - 2.f * dot, 1e-12f));
      const float z = beta + alpha * expf(-d);
      const float sim = (z >= 0.f) ? z : 0.2f * z;
      if (sim > best) { best = sim; bm_ = m; }
    }
    sm_m[n] = bm_;
    sm_s[n] = best;
    atomicAdd(&cnt[bm_], 1);
  }
  __syncthreads();

  // Phase 3: masked weighted reduce of V to centers; add vcen; / (count+1)
  for (int t = tid; t < 384; t += 256) {
    const int m = t / 24, ch = t - m * 24;
    float acc = 0.f;
    for (int n = 0; n < 1024; n++) {
      if (sm_m[n] == m) acc += sm_s[n] * u2f(Vb[(size_t)n * 384 + ch]);
    }
    outc[m][ch] = (acc + vcen[m][ch]) / ((float)cnt[m] + 1.f);
  }
  __syncthreads();

  // Phase 4: broadcast back to tokens, in place into f-columns
  for (int n = tid; n < 1024; n += 256) {
    const int m = sm_m[n];
    const float s = sm_s[n];
#pragma unroll
    for (int ch = 0; ch < 24; ch++) Fb[(size_t)n * 384 + ch] = f2u(s * outc[m][ch]);
  }
}

// ---------------------------------------------------------------------------
// Workspace layout (floor 48.1 MB; G beyond that, adaptive; evidence from
// round-4 dispatch pattern says ws_size >= ~145 MB):
//   flag @0 | fv_w @256 | proj_w @590080 | fc1_w @884992 | fc2_w @5603584
//   fvb @10322176 | projb @10322944 | fc1b @10324480 | fc2b @10330624
//   Y1 bf16 16384x768 @10332416 | FV bf16 16384x384 @35498240 | G @48081152
// h (flag dtype) lives in d_out: proj writes, ln2 reads, fc2 RMWs in place.
// ---------------------------------------------------------------------------
extern "C" void kernel_launch(void* const* d_in, const int* in_sizes, int n_in,
                              void* d_out, int out_size, void* d_ws, size_t ws_size,
                              hipStream_t stream) {
  const void* x      = d_in[0];
  const void* ln1_w  = d_in[1];
  const void* ln1_b  = d_in[2];
  const void* f_w    = d_in[3];
  const void* f_b    = d_in[4];
  const void* v_w    = d_in[5];
  const void* v_b    = d_in[6];
  const void* proj_w = d_in[7];
  const void* proj_b = d_in[8];
  const void* alpha  = d_in[9];
  const void* beta   = d_in[10];
  const void* ln2_w  = d_in[11];
  const void* ln2_b  = d_in[12];
  const void* fc1_w  = d_in[13];
  const void* fc1_b  = d_in[14];
  const void* fc2_w  = d_in[15];
  const void* fc2_b  = d_in[16];

  char* ws = (char*)d_ws;
  int* flag  = (int*)(ws + 0);
  u16* fvw   = (u16*)(ws + 256);
  u16* prw   = (u16*)(ws + 590080);
  u16* f1w   = (u16*)(ws + 884992);
  u16* f2w   = (u16*)(ws + 5603584);
  u16* fvb   = (u16*)(ws + 10322176);
  u16* prb   = (u16*)(ws + 10322944);
  u16* f1b   = (u16*)(ws + 10324480);
  u16* f2b_  = (u16*)(ws + 10330624);
  u16* Y1    = (u16*)(ws + 10332416);
  u16* FV    = (u16*)(ws + 35498240);
  u16* Gext  = (u16*)(ws + 48081152);

  // fc1/fc2 chunk rows (multiple of 128), pure function of ws_size.
  const long extra = (long)ws_size - 48081152L;
  u16* G; long crows;
  if (extra >= (long)NTOK * HID_ * 2) { G = Gext; crows = NTOK; }
  else if (extra >= 128L * HID_ * 2) { G = Gext; crows = (extra / (HID_ * 2)) / 128 * 128; }
  else { G = FV; crows = 2048; }  // FV dead after proj; 2048*3072*2 = 12.58 MB fits

  detect_kernel<<<1, 64, 0, stream>>>((const unsigned*)x, flag);

  CvtArgs ca;
  ca.j[0] = {f_w,    fvw,            147456 / 4};
  ca.j[1] = {v_w,    fvw + 147456,   147456 / 4};
  ca.j[2] = {proj_w, prw,            147456 / 4};
  ca.j[3] = {fc1_w,  f1w,            2359296 / 4};
  ca.j[4] = {fc2_w,  f2w,            2359296 / 4};
  ca.j[5] = {f_b,    fvb,            192 / 4};
  ca.j[6] = {v_b,    fvb + 192,      192 / 4};
  ca.j[7] = {proj_b, prb,            768 / 4};
  ca.j[8] = {fc1_b,  f1b,            3072 / 4};
  ca.j[9] = {fc2_b,  f2b_,           768 / 4};
  cvt_kernel<<<dim3(2304, 10), 256, 0, stream>>>(ca, flag);

  // ln1(x) -> Y1 (bf16)
  ln_kernel<<<NTOK, 256, 0, stream>>>(x, ln1_w, ln1_b, Y1, flag);
  // FV = Y1 * [f_w; v_w]^T + [f_b; v_b]   (M=16384, N=384, K=768)
  mfma_gemm<0><<<dim3(128, 3), 256, 0, stream>>>(
      Y1, D_, fvw, D_, fvb, nullptr, FV, 384, D_, 0, flag);
  cluster_kernel<<<128, 256, 0, stream>>>(FV, alpha, beta, flag);
  // h = CL * proj_w^T + proj_b + x -> d_out (flag dtype). A = FV cols [0,192).
  mfma_gemm<2><<<dim3(128, 6), 256, 0, stream>>>(
      FV, 384, prw, INNER_, prb, x, d_out, D_, INNER_, 0, flag);
  // ln2(h) -> Y1 (bf16)
  ln_kernel<<<NTOK, 256, 0, stream>>>(d_out, ln2_w, ln2_b, Y1, flag);
  // fc1 -> G (gelu), fc2 + h residual -> d_out in place, chunked
  for (long t0 = 0; t0 < NTOK; t0 += crows) {
    const long ct = (t0 + crows <= NTOK) ? crows : (NTOK - t0);
    mfma_gemm<1><<<dim3(ct / 128, 24), 256, 0, stream>>>(
        Y1 + t0 * D_, D_, f1w, D_, f1b, nullptr, G, HID_, D_, 0, flag);
    mfma_gemm<2><<<dim3(ct / 128, 6), 256, 0, stream>>>(
        G, HID_, f2w, HID_, f2b_, d_out, d_out, D_, HID_, (long)t0, flag);
  }
}

// Round 6
// 615.504 us; speedup vs baseline: 5.8036x; 1.1567x over previous
//
#include <hip/hip_runtime.h>
#include <hip/hip_bf16.h>
#include <cmath>

typedef unsigned short u16;
typedef short short8 __attribute__((ext_vector_type(8)));   // 8 bf16 (4 VGPRs)
typedef float f32x4 __attribute__((ext_vector_type(4)));    // 4 fp32 acc

#define D_ 768
#define NTOK 16384      // B * N = 16 * 1024
#define INNER_ 192
#define HID_ 3072

__device__ __forceinline__ float u2f(u16 u) { return __uint_as_float((unsigned)u << 16); }
__device__ __forceinline__ u16 f2u(float f) {
  __hip_bfloat16 h = __float2bfloat16(f);
  u16 u; __builtin_memcpy(&u, &h, 2); return u;
}
// Flag-aware scalar load/store: harness tensors are f32 (flag=1) or bf16 (0).
__device__ __forceinline__ float ld1(const void* p, size_t i, int f32) {
  return f32 ? ((const float*)p)[i] : u2f(((const u16*)p)[i]);
}
__device__ __forceinline__ void st1(void* p, size_t i, float v, int f32) {
  if (f32) ((float*)p)[i] = v; else ((u16*)p)[i] = f2u(v);
}
__device__ __forceinline__ float gelu_exact(float v) {
  return 0.5f * v * (1.f + erff(v * 0.7071067811865476f));
}

// ---------------------------------------------------------------------------
// Dtype detector (verified round 4/5): flag 1 = f32 inputs, 0 = bf16 inputs.
// ---------------------------------------------------------------------------
__global__ __launch_bounds__(64) void detect_kernel(const unsigned* __restrict__ x,
                                                    int* __restrict__ flag) {
  int cnt = 0;
  for (int i = threadIdx.x; i < 512; i += 64) {
    const unsigned e0 = (x[i] >> 7) & 0xFFu;
    if (e0 >= 96u && e0 <= 144u) cnt++;
  }
#pragma unroll
  for (int o = 32; o > 0; o >>= 1) cnt += __shfl_down(cnt, o);
  if (threadIdx.x == 0) flag[0] = (cnt < 256) ? 1 : 0;
}

// ---------------------------------------------------------------------------
// Weight conversion to internal bf16 (10 jobs; grid.y = job id).
// ---------------------------------------------------------------------------
struct CvtJob { const void* src; u16* dst; int n4; };  // n4 = elems/4
struct CvtArgs { CvtJob j[10]; };

__global__ __launch_bounds__(256) void cvt_kernel(CvtArgs a, const int* __restrict__ flagp) {
  const int f32 = flagp[0];
  const CvtJob jb = a.j[blockIdx.y];
  const int i = blockIdx.x * 256 + threadIdx.x;
  if (i >= jb.n4) return;
  if (f32) {
    const float4 v = ((const float4*)jb.src)[i];
    const unsigned lo = (unsigned)f2u(v.x) | ((unsigned)f2u(v.y) << 16);
    const unsigned hi = (unsigned)f2u(v.z) | ((unsigned)f2u(v.w) << 16);
    ((uint2*)jb.dst)[i] = make_uint2(lo, hi);
  } else {
    ((uint2*)jb.dst)[i] = ((const uint2*)jb.src)[i];
  }
}

// ---------------------------------------------------------------------------
// Fused LayerNorm: stats + normalize, one block (256 thr) per token.
// Input flag dtype, ln params flag dtype, output internal bf16.
// ---------------------------------------------------------------------------
__global__ __launch_bounds__(256) void ln_kernel(const void* __restrict__ x,
                                                 const void* __restrict__ w,
                                                 const void* __restrict__ b,
                                                 u16* __restrict__ y,
                                                 const int* __restrict__ flagp) {
  const int fl = flagp[0];
  const size_t t = blockIdx.x;
  float v[3];
  float s = 0.f, s2 = 0.f;
#pragma unroll
  for (int i = 0; i < 3; i++) {
    v[i] = ld1(x, t * D_ + threadIdx.x + 256 * i, fl);
    s += v[i];
    s2 += v[i] * v[i];
  }
#pragma unroll
  for (int o = 32; o > 0; o >>= 1) {
    s += __shfl_down(s, o);
    s2 += __shfl_down(s2, o);
  }
  __shared__ float ps[4], ps2[4];
  __shared__ float smu, srstd;
  const int wid = threadIdx.x >> 6, lane = threadIdx.x & 63;
  if (lane == 0) { ps[wid] = s; ps2[wid] = s2; }
  __syncthreads();
  if (threadIdx.x == 0) {
    const float a = ps[0] + ps[1] + ps[2] + ps[3];
    const float a2 = ps2[0] + ps2[1] + ps2[2] + ps2[3];
    const float mu = a * (1.f / D_);
    smu = mu;
    srstd = rsqrtf(a2 * (1.f / D_) - mu * mu + 1e-5f);
  }
  __syncthreads();
  const float mu = smu, rstd = srstd;
#pragma unroll
  for (int i = 0; i < 3; i++) {
    const int c = threadIdx.x + 256 * i;
    y[t * D_ + c] = f2u((v[i] - mu) * rstd * ld1(w, c, fl) + ld1(b, c, fl));
  }
}

// ---------------------------------------------------------------------------
// MFMA GEMM (m97 structure): C[M x N] = A[M x K] * B[N x K]^T + bias.
// A, B internal bf16 (u16), row strides lda/ldb (elements), K % 32 == 0.
// 128x128 tile, 4 waves, each wave 4x4 grid of 16x16x32 MFMA tiles.
// Staging: global_load_lds width 16, LDS [128][32] bf16 row-major (no pad).
// EPI 0: C bf16 = acc+bias | 1: C bf16 = gelu(acc+bias)
// EPI 2: C flagdt = acc+bias + res_flagdt   (res may alias C; same-lane RMW)
// res/C rows offset by row0.
// ---------------------------------------------------------------------------
template <int EPI>
__global__ __launch_bounds__(256) void mfma_gemm(const u16* __restrict__ A, int lda,
                                                 const u16* __restrict__ B, int ldb,
                                                 const u16* __restrict__ bias,
                                                 const void* __restrict__ res,
                                                 void* __restrict__ C, int ldc,
                                                 int K, int row0,
                                                 const int* __restrict__ flagp) {
  const int fl = flagp[0];
  __shared__ __align__(16) u16 Asb[128 * 32];
  __shared__ __align__(16) u16 Bsb[128 * 32];
  const int tid = threadIdx.x;
  const int lane = tid & 63;
  const int wv = tid >> 6;
  const int bm = blockIdx.x * 128;
  const int bn = blockIdx.y * 128;
  const int wm = (wv & 1) * 64;
  const int wn = (wv >> 1) * 64;
  // Staging chunks: chunk c (8 bf16) -> row c>>2, k-off (c&3)*8; LDS byte c*16.
  const int c0 = tid, c1 = tid + 256;
  const u16* Ag0 = A + (size_t)(bm + (c0 >> 2)) * lda + (c0 & 3) * 8;
  const u16* Ag1 = A + (size_t)(bm + (c1 >> 2)) * lda + (c1 & 3) * 8;
  const u16* Bg0 = B + (size_t)(bn + (c0 >> 2)) * ldb + (c0 & 3) * 8;
  const u16* Bg1 = B + (size_t)(bn + (c1 >> 2)) * ldb + (c1 & 3) * 8;
  u16* la0 = &Asb[c0 * 8];
  u16* la1 = &Asb[c1 * 8];
  u16* lb0 = &Bsb[c0 * 8];
  u16* lb1 = &Bsb[c1 * 8];

  f32x4 acc[4][4];
#pragma unroll
  for (int i = 0; i < 4; i++)
#pragma unroll
    for (int j = 0; j < 4; j++) acc[i][j] = (f32x4){0.f, 0.f, 0.f, 0.f};

  const int ml = lane & 15;
  const int kq = (lane >> 4) * 8;

  for (int k0 = 0; k0 < K; k0 += 32) {
    __syncthreads();  // all waves done reading previous tile
    __builtin_amdgcn_global_load_lds(
        (const __attribute__((address_space(1))) void*)(Ag0 + k0),
        (__attribute__((address_space(3))) void*)la0, 16, 0, 0);
    __builtin_amdgcn_global_load_lds(
        (const __attribute__((address_space(1))) void*)(Ag1 + k0),
        (__attribute__((address_space(3))) void*)la1, 16, 0, 0);
    __builtin_amdgcn_global_load_lds(
        (const __attribute__((address_space(1))) void*)(Bg0 + k0),
        (__attribute__((address_space(3))) void*)lb0, 16, 0, 0);
    __builtin_amdgcn_global_load_lds(
        (const __attribute__((address_space(1))) void*)(Bg1 + k0),
        (__attribute__((address_space(3))) void*)lb1, 16, 0, 0);
    __syncthreads();  // vmcnt(0) drain => staging complete
    short8 af[4], bf[4];
#pragma unroll
    for (int i = 0; i < 4; i++) {
      af[i] = *(const short8*)&Asb[(wm + i * 16 + ml) * 32 + kq];
      bf[i] = *(const short8*)&Bsb[(wn + i * 16 + ml) * 32 + kq];
    }
#pragma unroll
    for (int i = 0; i < 4; i++)
#pragma unroll
      for (int j = 0; j < 4; j++)
        acc[i][j] = __builtin_amdgcn_mfma_f32_16x16x32_bf16(af[i], bf[j], acc[i][j], 0, 0, 0);
  }

  // Epilogue. C/D layout: col = lane&15, row = (lane>>4)*4 + reg.
  const int qr = (lane >> 4) * 4;
#pragma unroll
  for (int i = 0; i < 4; i++) {
#pragma unroll
    for (int j = 0; j < 4; j++) {
      const int colg = bn + wn + j * 16 + ml;
      const float bb = u2f(bias[colg]);
#pragma unroll
      for (int r = 0; r < 4; r++) {
        const size_t row = (size_t)row0 + bm + wm + i * 16 + qr + r;
        float v = acc[i][j][r] + bb;
        if (EPI == 1) v = gelu_exact(v);
        if (EPI == 2) {
          v += ld1(res, row * ldc + colg, fl);
          st1(C, row * ldc + colg, v, fl);
        } else {
          ((u16*)C)[row * ldc + colg] = f2u(v);
        }
      }
    }
  }
}

// ---------------------------------------------------------------------------
// Cluster kernel, LDS-staged: one block (512 thr) per (batch, head); 128 blocks.
// FV: internal bf16 (16384 tokens x 384): cols [0,192) = f, [192,384) = v.
// Stages the 1024x24 head slice into LDS (48 KB) -- F first (pool f, argmax),
// then V over the same buffer (pool v, reduce). CL written in place into the
// f-columns. Static LDS ~60.7 KB.
// ---------------------------------------------------------------------------
__global__ __launch_bounds__(512) void cluster_kernel(u16* __restrict__ FV,
                                                      const void* __restrict__ alpha_p,
                                                      const void* __restrict__ beta_p,
                                                      const int* __restrict__ flagp) {
  const int fl = flagp[0];
  const int be = blockIdx.x;       // 0..127
  const int b = be >> 3, e = be & 7;
  const int tid = threadIdx.x;
  const float alpha = ld1(alpha_p, 0, fl), beta = ld1(beta_p, 0, fl);

  __shared__ __align__(16) u16 S[1024 * 24];   // staged F, then V (48 KB)
  __shared__ float cn[16][24];     // f centers, normalized in place
  __shared__ float vcen[16][24];   // v centers
  __shared__ float outc[16][24];   // reduced center features
  __shared__ float cnorm[16];
  __shared__ int cnt[16];
  __shared__ int sm_m[1024];       // per-token argmax center
  __shared__ float sm_s[1024];     // per-token sim at argmax

  u16* Fg = FV + ((size_t)b * 1024) * 384 + e * 24;  // token stride 384
  const u16* Vg = Fg + 192;

  // ---- Stage F slice: 1024 tokens x 48 B = 3072 x 16 B chunks, coalesced.
  for (int c = tid; c < 3072; c += 512) {
    const int n = c / 3, q = c - n * 3;
    *(uint4*)&S[n * 24 + q * 8] = *(const uint4*)(Fg + (size_t)n * 384 + q * 8);
  }
  if (tid < 16) cnt[tid] = 0;
  __syncthreads();

  // ---- Pool f centers (16 m x 24 ch tasks; 8x8 spatial mean) from LDS.
  for (int t = tid; t < 384; t += 512) {
    const int m = t / 24, ch = t - m * 24;
    const int pw = m >> 2, ph = m & 3;        // m = pw*4 + ph
    float sum = 0.f;
    for (int dw = 0; dw < 8; dw++) {
      const int base = (pw * 8 + dw) * 32 + ph * 8;  // n = w*32 + h
      for (int dh = 0; dh < 8; dh++) sum += u2f(S[(base + dh) * 24 + ch]);
    }
    cn[m][ch] = sum * (1.f / 64.f);
  }
  __syncthreads();
  if (tid < 16) {
    float s = 0.f;
    for (int ch = 0; ch < 24; ch++) { const float v = cn[tid][ch]; s += v * v; }
    cnorm[tid] = fmaxf(sqrtf(s), 1e-12f);
  }
  __syncthreads();
  for (int t = tid; t < 384; t += 512) {
    const int m = t / 24, ch = t - m * 24;
    cn[m][ch] /= cnorm[m];
  }
  __syncthreads();

  // ---- Phase 2: per-token normalize, sim to 16 centers, argmax (first-max).
  for (int n = tid; n < 1024; n += 512) {
    float xf[24];
    float s = 0.f;
#pragma unroll
    for (int ch = 0; ch < 24; ch++) {
      xf[ch] = u2f(S[n * 24 + ch]);
      s += xf[ch] * xf[ch];
    }
    const float rn = 1.f / fmaxf(sqrtf(s), 1e-12f);
    float best = -3.4e38f;
    int bm_ = 0;
    for (int m = 0; m < 16; m++) {
      float dot = 0.f;
#pragma unroll
      for (int ch = 0; ch < 24; ch++) dot += cn[m][ch] * xf[ch];
      dot *= rn;
      const float d = sqrtf(fmaxf(2.f - 2.f * dot, 1e-12f));
      const float z = beta + alpha * expf(-d);
      const float sim = (z >= 0.f) ? z : 0.2f * z;
      if (sim > best) { best = sim; bm_ = m; }
    }
    sm_m[n] = bm_;
    sm_s[n] = best;
    atomicAdd(&cnt[bm_], 1);
  }
  __syncthreads();  // all reads of F-in-LDS done

  // ---- Stage V slice over the same LDS buffer.
  for (int c = tid; c < 3072; c += 512) {
    const int n = c / 3, q = c - n * 3;
    *(uint4*)&S[n * 24 + q * 8] = *(const uint4*)(Vg + (size_t)n * 384 + q * 8);
  }
  __syncthreads();

  // ---- Pool v centers from LDS.
  for (int t = tid; t < 384; t += 512) {
    const int m = t / 24, ch = t - m * 24;
    const int pw = m >> 2, ph = m & 3;
    float sum = 0.f;
    for (int dw = 0; dw < 8; dw++) {
      const int base = (pw * 8 + dw) * 32 + ph * 8;
      for (int dh = 0; dh < 8; dh++) sum += u2f(S[(base + dh) * 24 + ch]);
    }
    vcen[m][ch] = sum * (1.f / 64.f);
  }
  __syncthreads();

  // ---- Phase 3: masked weighted reduce of V to centers (from LDS).
  for (int t = tid; t < 384; t += 512) {
    const int m = t / 24, ch = t - m * 24;
    float acc = 0.f;
    for (int n = 0; n < 1024; n++) {
      if (sm_m[n] == m) acc += sm_s[n] * u2f(S[n * 24 + ch]);
    }
    outc[m][ch] = (acc + vcen[m][ch]) / ((float)cnt[m] + 1.f);
  }
  __syncthreads();

  // ---- Phase 4: broadcast to tokens, vectorized in-place write to f-columns.
  for (int n = tid; n < 1024; n += 512) {
    const int m = sm_m[n];
    const float s = sm_s[n];
    unsigned w[12];
#pragma unroll
    for (int k = 0; k < 12; k++) {
      w[k] = (unsigned)f2u(s * outc[m][2 * k]) |
             ((unsigned)f2u(s * outc[m][2 * k + 1]) << 16);
    }
    uint4* dst = (uint4*)(Fg + (size_t)n * 384);
    dst[0] = make_uint4(w[0], w[1], w[2], w[3]);
    dst[1] = make_uint4(w[4], w[5], w[6], w[7]);
    dst[2] = make_uint4(w[8], w[9], w[10], w[11]);
  }
}

// ---------------------------------------------------------------------------
// Workspace layout (floor 48.1 MB; G beyond that, adaptive; round-4 evidence:
// ws_size >= ~145 MB):
//   flag @0 | fv_w @256 | proj_w @590080 | fc1_w @884992 | fc2_w @5603584
//   fvb @10322176 | projb @10322944 | fc1b @10324480 | fc2b @10330624
//   Y1 bf16 16384x768 @10332416 | FV bf16 16384x384 @35498240 | G @48081152
// h (flag dtype) lives in d_out: proj writes, ln2 reads, fc2 RMWs in place.
// ---------------------------------------------------------------------------
extern "C" void kernel_launch(void* const* d_in, const int* in_sizes, int n_in,
                              void* d_out, int out_size, void* d_ws, size_t ws_size,
                              hipStream_t stream) {
  const void* x      = d_in[0];
  const void* ln1_w  = d_in[1];
  const void* ln1_b  = d_in[2];
  const void* f_w    = d_in[3];
  const void* f_b    = d_in[4];
  const void* v_w    = d_in[5];
  const void* v_b    = d_in[6];
  const void* proj_w = d_in[7];
  const void* proj_b = d_in[8];
  const void* alpha  = d_in[9];
  const void* beta   = d_in[10];
  const void* ln2_w  = d_in[11];
  const void* ln2_b  = d_in[12];
  const void* fc1_w  = d_in[13];
  const void* fc1_b  = d_in[14];
  const void* fc2_w  = d_in[15];
  const void* fc2_b  = d_in[16];

  char* ws = (char*)d_ws;
  int* flag  = (int*)(ws + 0);
  u16* fvw   = (u16*)(ws + 256);
  u16* prw   = (u16*)(ws + 590080);
  u16* f1w   = (u16*)(ws + 884992);
  u16* f2w   = (u16*)(ws + 5603584);
  u16* fvb   = (u16*)(ws + 10322176);
  u16* prb   = (u16*)(ws + 10322944);
  u16* f1b   = (u16*)(ws + 10324480);
  u16* f2b_  = (u16*)(ws + 10330624);
  u16* Y1    = (u16*)(ws + 10332416);
  u16* FV    = (u16*)(ws + 35498240);
  u16* Gext  = (u16*)(ws + 48081152);

  // fc1/fc2 chunk rows (multiple of 128), pure function of ws_size.
  const long extra = (long)ws_size - 48081152L;
  u16* G; long crows;
  if (extra >= (long)NTOK * HID_ * 2) { G = Gext; crows = NTOK; }
  else if (extra >= 128L * HID_ * 2) { G = Gext; crows = (extra / (HID_ * 2)) / 128 * 128; }
  else { G = FV; crows = 2048; }  // FV dead after proj; 2048*3072*2 = 12.58 MB fits

  detect_kernel<<<1, 64, 0, stream>>>((const unsigned*)x, flag);

  CvtArgs ca;
  ca.j[0] = {f_w,    fvw,            147456 / 4};
  ca.j[1] = {v_w,    fvw + 147456,   147456 / 4};
  ca.j[2] = {proj_w, prw,            147456 / 4};
  ca.j[3] = {fc1_w,  f1w,            2359296 / 4};
  ca.j[4] = {fc2_w,  f2w,            2359296 / 4};
  ca.j[5] = {f_b,    fvb,            192 / 4};
  ca.j[6] = {v_b,    fvb + 192,      192 / 4};
  ca.j[7] = {proj_b, prb,            768 / 4};
  ca.j[8] = {fc1_b,  f1b,            3072 / 4};
  ca.j[9] = {fc2_b,  f2b_,           768 / 4};
  cvt_kernel<<<dim3(2304, 10), 256, 0, stream>>>(ca, flag);

  // ln1(x) -> Y1 (bf16)
  ln_kernel<<<NTOK, 256, 0, stream>>>(x, ln1_w, ln1_b, Y1, flag);
  // FV = Y1 * [f_w; v_w]^T + [f_b; v_b]   (M=16384, N=384, K=768)
  mfma_gemm<0><<<dim3(128, 3), 256, 0, stream>>>(
      Y1, D_, fvw, D_, fvb, nullptr, FV, 384, D_, 0, flag);
  cluster_kernel<<<128, 512, 0, stream>>>(FV, alpha, beta, flag);
  // h = CL * proj_w^T + proj_b + x -> d_out (flag dtype). A = FV cols [0,192).
  mfma_gemm<2><<<dim3(128, 6), 256, 0, stream>>>(
      FV, 384, prw, INNER_, prb, x, d_out, D_, INNER_, 0, flag);
  // ln2(h) -> Y1 (bf16)
  ln_kernel<<<NTOK, 256, 0, stream>>>(d_out, ln2_w, ln2_b, Y1, flag);
  // fc1 -> G (gelu), fc2 + h residual -> d_out in place, chunked
  for (long t0 = 0; t0 < NTOK; t0 += crows) {
    const long ct = (t0 + crows <= NTOK) ? crows : (NTOK - t0);
    mfma_gemm<1><<<dim3(ct / 128, 24), 256, 0, stream>>>(
        Y1 + t0 * D_, D_, f1w, D_, f1b, nullptr, G, HID_, D_, 0, flag);
    mfma_gemm<2><<<dim3(ct / 128, 6), 256, 0, stream>>>(
        G, HID_, f2w, HID_, f2b_, d_out, d_out, D_, HID_, (int)t0, flag);
  }
}